// Round 1
// baseline (393.272 us; speedup 1.0000x reference)
//
#include <hip/hip_runtime.h>
#include <math.h>

#define N_NODES 10000
#define E_EDGES 320000
#define F_IN    384
#define H1      256
#define H2      128
#define A1      64

// ---------- weight repack: W (O x K, row-major) -> Wq[(kb*O + o)*4 + j] = W[o*K + kb*4 + j]
__global__ void k_repack(const float* __restrict__ W, float* __restrict__ Wq, int K, int O) {
    int idx = blockIdx.x * blockDim.x + threadIdx.x;
    if (idx < O * K) {
        int o = idx / K;
        int k = idx - o * K;
        int kb = k >> 2, j = k & 3;
        Wq[(kb * O + o) * 4 + j] = W[idx];
    }
}

// ---------- degree count
__global__ void k_deg(const int* __restrict__ tgt, int* __restrict__ deg) {
    int e = blockIdx.x * blockDim.x + threadIdx.x;
    if (e < E_EDGES) atomicAdd(&deg[tgt[e]], 1);
}

// ---------- exclusive scan over deg (single block, 256 threads, 40 elems/thread)
__global__ void k_scan(const int* __restrict__ deg, int* __restrict__ off,
                       int* __restrict__ cursor, float* __restrict__ inv) {
    const int CH = 40;  // 256*40 = 10240 >= N_NODES
    int tid = threadIdx.x;
    int base = tid * CH;
    int sum = 0;
    int local[CH];
    #pragma unroll
    for (int i = 0; i < CH; i++) {
        int idx = base + i;
        int v = (idx < N_NODES) ? deg[idx] : 0;
        local[i] = sum;   // exclusive within this thread's chunk
        sum += v;
    }
    __shared__ int sd[256];
    sd[tid] = sum;
    __syncthreads();
    for (int d = 1; d < 256; d <<= 1) {
        int v = (tid >= d) ? sd[tid - d] : 0;
        __syncthreads();
        sd[tid] += v;
        __syncthreads();
    }
    int excl = sd[tid] - sum;
    #pragma unroll
    for (int i = 0; i < CH; i++) {
        int idx = base + i;
        if (idx < N_NODES) {
            int o = local[i] + excl;
            off[idx] = o;
            cursor[idx] = o;
            inv[idx] = 1.0f / (float)(deg[idx] + 1);
        }
    }
    if (tid == 255) off[N_NODES] = sd[255];
}

// ---------- CSR bin fill
__global__ void k_fill(const int* __restrict__ src, const int* __restrict__ tgt,
                       int* __restrict__ cursor, int* __restrict__ csr) {
    int e = blockIdx.x * blockDim.x + threadIdx.x;
    if (e < E_EDGES) {
        int t = tgt[e];
        int p = atomicAdd(&cursor[t], 1);
        csr[p] = src[e];
    }
}

// ---------- fc1: h = relu(x @ W1^T + b1)   (block = 256 threads = 256 output cols, 16 rows/block)
__global__ __launch_bounds__(256) void k_fc1(const float* __restrict__ x,
                                             const float* __restrict__ W1q,
                                             const float* __restrict__ b1,
                                             float* __restrict__ h) {
    const int MT = 16;
    int row0 = blockIdx.x * MT;
    int o = threadIdx.x;
    float acc[MT];
    float bb = b1[o];
    #pragma unroll
    for (int m = 0; m < MT; m++) acc[m] = bb;
    const float4* W4 = (const float4*)W1q;
    const float4* x4 = (const float4*)x;
    for (int kb = 0; kb < F_IN / 4; kb++) {
        float4 w = W4[kb * H1 + o];
        #pragma unroll
        for (int m = 0; m < MT; m++) {
            // address is block-uniform -> scalar loads on the SMEM pipe
            float4 xv = x4[(row0 + m) * (F_IN / 4) + kb];
            acc[m] += xv.x * w.x + xv.y * w.y + xv.z * w.z + xv.w * w.w;
        }
    }
    #pragma unroll
    for (int m = 0; m < MT; m++) {
        float v = acc[m];
        h[(row0 + m) * H1 + o] = v > 0.f ? v : 0.f;
    }
}

// ---------- aggregation: hout[t] = 0.7*hin[t] + 0.3*inv[t]*sum_{s in N(t)} hin[s]
// one node per block of 64 threads, float4 per lane (64*16B = 1KB row)
__global__ __launch_bounds__(64) void k_agg(const float* __restrict__ hin,
                                            float* __restrict__ hout,
                                            const int* __restrict__ off,
                                            const int* __restrict__ csr,
                                            const float* __restrict__ inv) {
    int t = blockIdx.x;
    int tid = threadIdx.x;
    int s0 = off[t], s1 = off[t + 1];
    const float4* hin4 = (const float4*)hin;
    float4 acc = make_float4(0.f, 0.f, 0.f, 0.f);
    for (int e = s0; e < s1; e++) {
        int s = csr[e];  // uniform -> scalar load
        float4 v = hin4[s * (H1 / 4) + tid];
        acc.x += v.x; acc.y += v.y; acc.z += v.z; acc.w += v.w;
    }
    float iv = 0.3f * inv[t];
    float4 hs = hin4[t * (H1 / 4) + tid];
    float4 r;
    r.x = 0.7f * hs.x + iv * acc.x;
    r.y = 0.7f * hs.y + iv * acc.y;
    r.z = 0.7f * hs.z + iv * acc.z;
    r.w = 0.7f * hs.w + iv * acc.w;
    ((float4*)hout)[t * (H1 / 4) + tid] = r;
}

// ---------- fc2: out = relu(h @ W2^T + b2)  (block = 128 threads = 128 cols, 16 rows/block)
__global__ __launch_bounds__(128) void k_fc2(const float* __restrict__ h,
                                             const float* __restrict__ W2q,
                                             const float* __restrict__ b2,
                                             float* __restrict__ out) {
    const int MT = 16;
    int row0 = blockIdx.x * MT;
    int o = threadIdx.x;
    float acc[MT];
    float bb = b2[o];
    #pragma unroll
    for (int m = 0; m < MT; m++) acc[m] = bb;
    const float4* W4 = (const float4*)W2q;
    const float4* h4 = (const float4*)h;
    for (int kb = 0; kb < H1 / 4; kb++) {
        float4 w = W4[kb * H2 + o];
        #pragma unroll
        for (int m = 0; m < MT; m++) {
            float4 hv = h4[(row0 + m) * (H1 / 4) + kb];
            acc[m] += hv.x * w.x + hv.y * w.y + hv.z * w.z + hv.w * w.w;
        }
    }
    #pragma unroll
    for (int m = 0; m < MT; m++) {
        float v = acc[m];
        out[(row0 + m) * H2 + o] = v > 0.f ? v : 0.f;
    }
}

// ---------- attention head: att = sigmoid(relu(out @ Wa1^T + ba1) @ Wa2^T + ba2)
// 4 nodes per 256-thread block; 64 lanes per node (one per hidden unit)
__global__ __launch_bounds__(256) void k_att(const float* __restrict__ out,
                                             const float* __restrict__ Wa1,
                                             const float* __restrict__ ba1,
                                             const float* __restrict__ Wa2,
                                             const float* __restrict__ ba2,
                                             float* __restrict__ att) {
    int node = blockIdx.x * 4 + (threadIdx.x >> 6);
    int j = threadIdx.x & 63;
    float acc = ba1[j];
    const float4* orow = (const float4*)(out + node * H2);
    const float4* w4 = (const float4*)(Wa1 + j * H2);
    #pragma unroll
    for (int kb = 0; kb < H2 / 4; kb++) {
        float4 w = w4[kb];
        float4 xv = orow[kb];  // wave-uniform -> scalar load
        acc += w.x * xv.x + w.y * xv.y + w.z * xv.z + w.w * xv.w;
    }
    float z = acc > 0.f ? acc : 0.f;
    float v = z * Wa2[j];
    #pragma unroll
    for (int d = 32; d > 0; d >>= 1) v += __shfl_down(v, d, 64);
    if (j == 0) att[node] = 1.f / (1.f + expf(-v));
}

extern "C" void kernel_launch(void* const* d_in, const int* in_sizes, int n_in,
                              void* d_out, int out_size, void* d_ws, size_t ws_size,
                              hipStream_t stream) {
    const float* x   = (const float*)d_in[0];
    const int*   ei  = (const int*)d_in[1];   // (2, E): row0=src, row1=tgt
    const float* W1  = (const float*)d_in[2];
    const float* b1  = (const float*)d_in[3];
    const float* W2  = (const float*)d_in[4];
    const float* b2  = (const float*)d_in[5];
    const float* Wa1 = (const float*)d_in[6];
    const float* ba1 = (const float*)d_in[7];
    const float* Wa2 = (const float*)d_in[8];
    const float* ba2 = (const float*)d_in[9];
    const int* src = ei;
    const int* tgt = ei + E_EDGES;

    float* out_mat = (float*)d_out;                 // N x 128
    float* att     = out_mat + N_NODES * H2;        // N x 1

    // workspace layout
    float* ws  = (float*)d_ws;
    float* h0  = ws;                      // N*H1
    float* h1  = h0 + N_NODES * H1;       // N*H1
    float* W1q = h1 + N_NODES * H1;       // F_IN*H1
    float* W2q = W1q + F_IN * H1;         // H1*H2
    float* inv = W2q + H1 * H2;           // N
    int* deg    = (int*)(inv + N_NODES);  // N
    int* off    = deg + N_NODES;          // N+1
    int* cursor = off + N_NODES + 1;      // N
    int* csr    = cursor + N_NODES;       // E

    hipMemsetAsync(deg, 0, N_NODES * sizeof(int), stream);

    // weight repacks
    k_repack<<<(F_IN * H1 + 255) / 256, 256, 0, stream>>>(W1, W1q, F_IN, H1);
    k_repack<<<(H1 * H2 + 255) / 256, 256, 0, stream>>>(W2, W2q, H1, H2);

    // CSR build
    k_deg<<<(E_EDGES + 255) / 256, 256, 0, stream>>>(tgt, deg);
    k_scan<<<1, 256, 0, stream>>>(deg, off, cursor, inv);
    k_fill<<<(E_EDGES + 255) / 256, 256, 0, stream>>>(src, tgt, cursor, csr);

    // fc1
    k_fc1<<<N_NODES / 16, 256, 0, stream>>>(x, W1q, b1, h0);

    // 2 aggregation passes
    k_agg<<<N_NODES, 64, 0, stream>>>(h0, h1, off, csr, inv);
    k_agg<<<N_NODES, 64, 0, stream>>>(h1, h0, off, csr, inv);

    // fc2 -> out
    k_fc2<<<N_NODES / 16, 128, 0, stream>>>(h0, W2q, b2, out_mat);

    // attention -> att
    k_att<<<N_NODES / 4, 256, 0, stream>>>(out_mat, Wa1, ba1, Wa2, ba2, att);
}

// Round 2
// 279.498 us; speedup vs baseline: 1.4071x; 1.4071x over previous
//
#include <hip/hip_runtime.h>
#include <math.h>

#define N_NODES 10000
#define E_EDGES 320000
#define F_IN    384
#define H1      256
#define H2      128

typedef __attribute__((ext_vector_type(8))) short bf16x8;
typedef __attribute__((ext_vector_type(4))) float f32x4;

static __device__ inline unsigned short f2bf(float f) {
    unsigned u = __float_as_uint(f);
    unsigned r = (u + 0x7fffu + ((u >> 16) & 1u)) >> 16;   // RNE
    return (unsigned short)r;
}

// ---------- fp32 -> bf16 bulk convert (4 elems/thread)
__global__ void k_f2b(const float* __restrict__ in, unsigned short* __restrict__ out, int n4) {
    int i = blockIdx.x * blockDim.x + threadIdx.x;
    if (i < n4) {
        float4 v = ((const float4*)in)[i];
        ushort4 o;
        o.x = f2bf(v.x); o.y = f2bf(v.y); o.z = f2bf(v.z); o.w = f2bf(v.w);
        ((ushort4*)out)[i] = o;
    }
}

// ---------- degree count
__global__ void k_deg(const int* __restrict__ tgt, int* __restrict__ deg) {
    int e = blockIdx.x * blockDim.x + threadIdx.x;
    if (e < E_EDGES) atomicAdd(&deg[tgt[e]], 1);
}

// ---------- exclusive scan over deg (single block, 1024 threads, 10 elems/thread)
__global__ __launch_bounds__(1024) void k_scan(const int* __restrict__ deg, int* __restrict__ off,
                                               int* __restrict__ cursor, float* __restrict__ inv) {
    const int CH = 10;  // 1024*10 = 10240 >= N_NODES
    int tid = threadIdx.x;
    int base = tid * CH;
    int sum = 0;
    int local[CH];
    #pragma unroll
    for (int i = 0; i < CH; i++) {
        int idx = base + i;
        int v = (idx < N_NODES) ? deg[idx] : 0;
        local[i] = sum;
        sum += v;
    }
    __shared__ int sd[1024];
    sd[tid] = sum;
    __syncthreads();
    for (int d = 1; d < 1024; d <<= 1) {
        int v = (tid >= d) ? sd[tid - d] : 0;
        __syncthreads();
        sd[tid] += v;
        __syncthreads();
    }
    int excl = sd[tid] - sum;
    #pragma unroll
    for (int i = 0; i < CH; i++) {
        int idx = base + i;
        if (idx < N_NODES) {
            int o = local[i] + excl;
            off[idx] = o;
            cursor[idx] = o;
            inv[idx] = 1.0f / (float)(deg[idx] + 1);
        }
    }
    if (tid == 1023) off[N_NODES] = sd[1023];
}

// ---------- CSR bin fill
__global__ void k_fill(const int* __restrict__ src, const int* __restrict__ tgt,
                       int* __restrict__ cursor, int* __restrict__ csr) {
    int e = blockIdx.x * blockDim.x + threadIdx.x;
    if (e < E_EDGES) {
        int t = tgt[e];
        int p = atomicAdd(&cursor[t], 1);
        csr[p] = src[e];
    }
}

// ---------- fc1 MFMA: h = relu(x @ W1^T + b1), bf16 in, bf16 out
// block = 256 = 4 waves; wave w covers N cols [w*64, w*64+64); block covers 16 rows
__global__ __launch_bounds__(256) void k_fc1(const unsigned short* __restrict__ xb,
                                             const unsigned short* __restrict__ w1b,
                                             const float* __restrict__ b1,
                                             unsigned short* __restrict__ h) {
    int wave = threadIdx.x >> 6;
    int lane = threadIdx.x & 63;
    int m0 = blockIdx.x * 16;
    int nbase = wave * 64;
    int ml = lane & 15, quad = lane >> 4;
    // A frag: A[m = lane&15][k = quad*8 + j], 8 contiguous bf16
    const bf16x8* Arow = (const bf16x8*)(xb + (size_t)(m0 + ml) * F_IN + quad * 8);
    const bf16x8* Brow[4];
    #pragma unroll
    for (int j = 0; j < 4; j++)
        Brow[j] = (const bf16x8*)(w1b + (size_t)(nbase + j * 16 + ml) * F_IN + quad * 8);
    f32x4 acc[4] = {{0,0,0,0},{0,0,0,0},{0,0,0,0},{0,0,0,0}};
    for (int kk = 0; kk < F_IN / 32; kk++) {
        bf16x8 a = Arow[kk * 4];   // step 32 elems = 4 * bf16x8
        #pragma unroll
        for (int j = 0; j < 4; j++) {
            bf16x8 b = Brow[j][kk * 4];
            acc[j] = __builtin_amdgcn_mfma_f32_16x16x32_bf16(a, b, acc[j], 0, 0, 0);
        }
    }
    // C/D: col = lane&15 (within 16), row = quad*4 + r
    #pragma unroll
    for (int j = 0; j < 4; j++) {
        int col = nbase + j * 16 + ml;
        float bb = b1[col];
        #pragma unroll
        for (int r = 0; r < 4; r++) {
            float v = acc[j][r] + bb;
            v = v > 0.f ? v : 0.f;
            h[(size_t)(m0 + quad * 4 + r) * H1 + col] = f2bf(v);
        }
    }
}

// ---------- aggregation (bf16 h): hout[t] = 0.7*hin[t] + 0.3*inv[t]*sum_{s in N(t)} hin[s]
// one node per 64-thread block; lane handles 4 bf16 = 8 B; wave reads 512 B/edge coalesced
__global__ __launch_bounds__(64) void k_agg(const unsigned short* __restrict__ hin,
                                            unsigned short* __restrict__ hout,
                                            const int* __restrict__ off,
                                            const int* __restrict__ csr,
                                            const float* __restrict__ inv) {
    int t = blockIdx.x;
    int tid = threadIdx.x;
    int s0 = off[t], s1 = off[t + 1];
    const uint2* base = (const uint2*)hin;
    float a0 = 0.f, a1 = 0.f, a2 = 0.f, a3 = 0.f;
    for (int e = s0; e < s1; e++) {
        int s = csr[e];  // wave-uniform -> scalar load
        uint2 v = base[(size_t)s * (H1 / 4) + tid];
        a0 += __uint_as_float(v.x << 16);
        a1 += __uint_as_float(v.x & 0xffff0000u);
        a2 += __uint_as_float(v.y << 16);
        a3 += __uint_as_float(v.y & 0xffff0000u);
    }
    uint2 sv = base[(size_t)t * (H1 / 4) + tid];
    float iv = 0.3f * inv[t];
    float r0 = 0.7f * __uint_as_float(sv.x << 16)        + iv * a0;
    float r1 = 0.7f * __uint_as_float(sv.x & 0xffff0000u) + iv * a1;
    float r2 = 0.7f * __uint_as_float(sv.y << 16)        + iv * a2;
    float r3 = 0.7f * __uint_as_float(sv.y & 0xffff0000u) + iv * a3;
    uint2 ov;
    ov.x = (unsigned)f2bf(r0) | ((unsigned)f2bf(r1) << 16);
    ov.y = (unsigned)f2bf(r2) | ((unsigned)f2bf(r3) << 16);
    ((uint2*)hout)[(size_t)t * (H1 / 4) + tid] = ov;
}

// ---------- fc2 MFMA: out = relu(h @ W2^T + b2), bf16 in, fp32 out
// block = 128 = 2 waves; wave w covers cols [w*64, w*64+64); block covers 16 rows
__global__ __launch_bounds__(128) void k_fc2(const unsigned short* __restrict__ hb,
                                             const unsigned short* __restrict__ w2b,
                                             const float* __restrict__ b2,
                                             float* __restrict__ out) {
    int wave = threadIdx.x >> 6;
    int lane = threadIdx.x & 63;
    int m0 = blockIdx.x * 16;
    int nbase = wave * 64;
    int ml = lane & 15, quad = lane >> 4;
    const bf16x8* Arow = (const bf16x8*)(hb + (size_t)(m0 + ml) * H1 + quad * 8);
    const bf16x8* Brow[4];
    #pragma unroll
    for (int j = 0; j < 4; j++)
        Brow[j] = (const bf16x8*)(w2b + (size_t)(nbase + j * 16 + ml) * H1 + quad * 8);
    f32x4 acc[4] = {{0,0,0,0},{0,0,0,0},{0,0,0,0},{0,0,0,0}};
    for (int kk = 0; kk < H1 / 32; kk++) {
        bf16x8 a = Arow[kk * 4];
        #pragma unroll
        for (int j = 0; j < 4; j++) {
            bf16x8 b = Brow[j][kk * 4];
            acc[j] = __builtin_amdgcn_mfma_f32_16x16x32_bf16(a, b, acc[j], 0, 0, 0);
        }
    }
    #pragma unroll
    for (int j = 0; j < 4; j++) {
        int col = nbase + j * 16 + ml;
        float bb = b2[col];
        #pragma unroll
        for (int r = 0; r < 4; r++) {
            float v = acc[j][r] + bb;
            v = v > 0.f ? v : 0.f;
            out[(size_t)(m0 + quad * 4 + r) * H2 + col] = v;
        }
    }
}

// ---------- attention head: att = sigmoid(relu(out @ Wa1^T + ba1) @ Wa2^T + ba2)
// 4 nodes per 256-thread block; 64 lanes per node (one per hidden unit)
__global__ __launch_bounds__(256) void k_att(const float* __restrict__ out,
                                             const float* __restrict__ Wa1,
                                             const float* __restrict__ ba1,
                                             const float* __restrict__ Wa2,
                                             const float* __restrict__ ba2,
                                             float* __restrict__ att) {
    int node = blockIdx.x * 4 + (threadIdx.x >> 6);
    int j = threadIdx.x & 63;
    float acc = ba1[j];
    const float4* orow = (const float4*)(out + (size_t)node * H2);
    const float4* w4 = (const float4*)(Wa1 + (size_t)j * H2);
    #pragma unroll
    for (int kb = 0; kb < H2 / 4; kb++) {
        float4 w = w4[kb];
        float4 xv = orow[kb];  // wave-uniform -> scalar load
        acc += w.x * xv.x + w.y * xv.y + w.z * xv.z + w.w * xv.w;
    }
    float z = acc > 0.f ? acc : 0.f;
    float v = z * Wa2[j];
    #pragma unroll
    for (int d = 32; d > 0; d >>= 1) v += __shfl_down(v, d, 64);
    if (j == 0) att[node] = 1.f / (1.f + expf(-v));
}

extern "C" void kernel_launch(void* const* d_in, const int* in_sizes, int n_in,
                              void* d_out, int out_size, void* d_ws, size_t ws_size,
                              hipStream_t stream) {
    const float* x   = (const float*)d_in[0];
    const int*   ei  = (const int*)d_in[1];   // (2, E): row0=src, row1=tgt
    const float* W1  = (const float*)d_in[2];
    const float* b1  = (const float*)d_in[3];
    const float* W2  = (const float*)d_in[4];
    const float* b2  = (const float*)d_in[5];
    const float* Wa1 = (const float*)d_in[6];
    const float* ba1 = (const float*)d_in[7];
    const float* Wa2 = (const float*)d_in[8];
    const float* ba2 = (const float*)d_in[9];
    const int* src = ei;
    const int* tgt = ei + E_EDGES;

    float* out_mat = (float*)d_out;                 // N x 128
    float* att     = out_mat + N_NODES * H2;        // N x 1

    // workspace layout (bf16 buffers as ushort)
    unsigned short* xb  = (unsigned short*)d_ws;                 // N*F_IN
    unsigned short* w1b = xb  + (size_t)N_NODES * F_IN;          // H1*F_IN
    unsigned short* w2b = w1b + (size_t)H1 * F_IN;               // H2*H1
    unsigned short* h0b = w2b + (size_t)H2 * H1;                 // N*H1
    unsigned short* h1b = h0b + (size_t)N_NODES * H1;            // N*H1
    float* inv  = (float*)(h1b + (size_t)N_NODES * H1);          // N
    int* deg    = (int*)(inv + N_NODES);                         // N
    int* off    = deg + N_NODES;                                 // N+1
    int* cursor = off + N_NODES + 1;                             // N
    int* csr    = cursor + N_NODES;                              // E

    hipMemsetAsync(deg, 0, N_NODES * sizeof(int), stream);

    // dtype converts
    k_f2b<<<(N_NODES * F_IN / 4 + 255) / 256, 256, 0, stream>>>(x, xb, N_NODES * F_IN / 4);
    k_f2b<<<(H1 * F_IN / 4 + 255) / 256, 256, 0, stream>>>(W1, w1b, H1 * F_IN / 4);
    k_f2b<<<(H2 * H1 / 4 + 255) / 256, 256, 0, stream>>>(W2, w2b, H2 * H1 / 4);

    // CSR build
    k_deg<<<(E_EDGES + 255) / 256, 256, 0, stream>>>(tgt, deg);
    k_scan<<<1, 1024, 0, stream>>>(deg, off, cursor, inv);
    k_fill<<<(E_EDGES + 255) / 256, 256, 0, stream>>>(src, tgt, cursor, csr);

    // fc1 (MFMA)
    k_fc1<<<N_NODES / 16, 256, 0, stream>>>(xb, w1b, b1, h0b);

    // 2 aggregation passes (bf16)
    k_agg<<<N_NODES, 64, 0, stream>>>(h0b, h1b, off, csr, inv);
    k_agg<<<N_NODES, 64, 0, stream>>>(h1b, h0b, off, csr, inv);

    // fc2 (MFMA) -> out (fp32)
    k_fc2<<<N_NODES / 16, 128, 0, stream>>>(h0b, w2b, b2, out_mat);

    // attention -> att
    k_att<<<N_NODES / 4, 256, 0, stream>>>(out_mat, Wa1, ba1, Wa2, ba2, att);
}

// Round 3
// 237.846 us; speedup vs baseline: 1.6535x; 1.1751x over previous
//
#include <hip/hip_runtime.h>
#include <math.h>

#define N_NODES 10000
#define E_EDGES 320000
#define F_IN    384
#define H1      256
#define H2      128
#define A1      64

typedef __attribute__((ext_vector_type(8))) short bf16x8;
typedef __attribute__((ext_vector_type(4))) float f32x4;

static __device__ inline unsigned short f2bf(float f) {
    unsigned u = __float_as_uint(f);
    unsigned r = (u + 0x7fffu + ((u >> 16) & 1u)) >> 16;   // RNE
    return (unsigned short)r;
}

// ---------- fp32 -> bf16 bulk convert (4 elems/thread)
__global__ void k_f2b(const float* __restrict__ in, unsigned short* __restrict__ out, int n4) {
    int i = blockIdx.x * blockDim.x + threadIdx.x;
    if (i < n4) {
        float4 v = ((const float4*)in)[i];
        ushort4 o;
        o.x = f2bf(v.x); o.y = f2bf(v.y); o.z = f2bf(v.z); o.w = f2bf(v.w);
        ((ushort4*)out)[i] = o;
    }
}

// ---------- fused weight converts: W1, W2, Wa1 -> bf16 in one launch
__global__ void k_f2bw(const float* __restrict__ W1, const float* __restrict__ W2,
                       const float* __restrict__ Wa1,
                       unsigned short* __restrict__ w1b, unsigned short* __restrict__ w2b,
                       unsigned short* __restrict__ wa1b) {
    const int n1 = H1 * F_IN / 4;   // 24576
    const int n2 = H2 * H1 / 4;     // 8192
    const int n3 = A1 * H2 / 4;     // 2048
    int i = blockIdx.x * blockDim.x + threadIdx.x;
    const float4* src;
    ushort4* dst;
    int j;
    if (i < n1)            { src = (const float4*)W1;  dst = (ushort4*)w1b;  j = i; }
    else if (i < n1 + n2)  { src = (const float4*)W2;  dst = (ushort4*)w2b;  j = i - n1; }
    else if (i < n1 + n2 + n3) { src = (const float4*)Wa1; dst = (ushort4*)wa1b; j = i - n1 - n2; }
    else return;
    float4 v = src[j];
    ushort4 o;
    o.x = f2bf(v.x); o.y = f2bf(v.y); o.z = f2bf(v.z); o.w = f2bf(v.w);
    dst[j] = o;
}

// ---------- degree count
__global__ void k_deg(const int* __restrict__ tgt, int* __restrict__ deg) {
    int e = blockIdx.x * blockDim.x + threadIdx.x;
    if (e < E_EDGES) atomicAdd(&deg[tgt[e]], 1);
}

// ---------- exclusive scan over deg (single block, 1024 threads, 10 elems/thread)
__global__ __launch_bounds__(1024) void k_scan(const int* __restrict__ deg, int* __restrict__ off,
                                               int* __restrict__ cursor, float* __restrict__ inv) {
    const int CH = 10;  // 1024*10 = 10240 >= N_NODES
    int tid = threadIdx.x;
    int base = tid * CH;
    int sum = 0;
    int local[CH];
    #pragma unroll
    for (int i = 0; i < CH; i++) {
        int idx = base + i;
        int v = (idx < N_NODES) ? deg[idx] : 0;
        local[i] = sum;
        sum += v;
    }
    __shared__ int sd[1024];
    sd[tid] = sum;
    __syncthreads();
    for (int d = 1; d < 1024; d <<= 1) {
        int v = (tid >= d) ? sd[tid - d] : 0;
        __syncthreads();
        sd[tid] += v;
        __syncthreads();
    }
    int excl = sd[tid] - sum;
    #pragma unroll
    for (int i = 0; i < CH; i++) {
        int idx = base + i;
        if (idx < N_NODES) {
            int o = local[i] + excl;
            off[idx] = o;
            cursor[idx] = o;
            inv[idx] = 1.0f / (float)(deg[idx] + 1);
        }
    }
    if (tid == 1023) off[N_NODES] = sd[1023];
}

// ---------- CSR bin fill
__global__ void k_fill(const int* __restrict__ src, const int* __restrict__ tgt,
                       int* __restrict__ cursor, int* __restrict__ csr) {
    int e = blockIdx.x * blockDim.x + threadIdx.x;
    if (e < E_EDGES) {
        int t = tgt[e];
        int p = atomicAdd(&cursor[t], 1);
        csr[p] = src[e];
    }
}

// ---------- fc1 MFMA: h = relu(x @ W1^T + b1), bf16 in, bf16 out
__global__ __launch_bounds__(256) void k_fc1(const unsigned short* __restrict__ xb,
                                             const unsigned short* __restrict__ w1b,
                                             const float* __restrict__ b1,
                                             unsigned short* __restrict__ h) {
    int wave = threadIdx.x >> 6;
    int lane = threadIdx.x & 63;
    int m0 = blockIdx.x * 16;
    int nbase = wave * 64;
    int ml = lane & 15, quad = lane >> 4;
    const bf16x8* Arow = (const bf16x8*)(xb + (size_t)(m0 + ml) * F_IN + quad * 8);
    const bf16x8* Brow[4];
    #pragma unroll
    for (int j = 0; j < 4; j++)
        Brow[j] = (const bf16x8*)(w1b + (size_t)(nbase + j * 16 + ml) * F_IN + quad * 8);
    f32x4 acc[4] = {{0,0,0,0},{0,0,0,0},{0,0,0,0},{0,0,0,0}};
    for (int kk = 0; kk < F_IN / 32; kk++) {
        bf16x8 a = Arow[kk * 4];
        #pragma unroll
        for (int j = 0; j < 4; j++) {
            bf16x8 b = Brow[j][kk * 4];
            acc[j] = __builtin_amdgcn_mfma_f32_16x16x32_bf16(a, b, acc[j], 0, 0, 0);
        }
    }
    #pragma unroll
    for (int j = 0; j < 4; j++) {
        int col = nbase + j * 16 + ml;
        float bb = b1[col];
        #pragma unroll
        for (int r = 0; r < 4; r++) {
            float v = acc[j][r] + bb;
            v = v > 0.f ? v : 0.f;
            h[(size_t)(m0 + quad * 4 + r) * H1 + col] = f2bf(v);
        }
    }
}

// ---------- aggregation (bf16 h)
__global__ __launch_bounds__(64) void k_agg(const unsigned short* __restrict__ hin,
                                            unsigned short* __restrict__ hout,
                                            const int* __restrict__ off,
                                            const int* __restrict__ csr,
                                            const float* __restrict__ inv) {
    int t = blockIdx.x;
    int tid = threadIdx.x;
    int s0 = off[t], s1 = off[t + 1];
    const uint2* base = (const uint2*)hin;
    float a0 = 0.f, a1 = 0.f, a2 = 0.f, a3 = 0.f;
    for (int e = s0; e < s1; e++) {
        int s = csr[e];
        uint2 v = base[(size_t)s * (H1 / 4) + tid];
        a0 += __uint_as_float(v.x << 16);
        a1 += __uint_as_float(v.x & 0xffff0000u);
        a2 += __uint_as_float(v.y << 16);
        a3 += __uint_as_float(v.y & 0xffff0000u);
    }
    uint2 sv = base[(size_t)t * (H1 / 4) + tid];
    float iv = 0.3f * inv[t];
    float r0 = 0.7f * __uint_as_float(sv.x << 16)         + iv * a0;
    float r1 = 0.7f * __uint_as_float(sv.x & 0xffff0000u) + iv * a1;
    float r2 = 0.7f * __uint_as_float(sv.y << 16)         + iv * a2;
    float r3 = 0.7f * __uint_as_float(sv.y & 0xffff0000u) + iv * a3;
    uint2 ov;
    ov.x = (unsigned)f2bf(r0) | ((unsigned)f2bf(r1) << 16);
    ov.y = (unsigned)f2bf(r2) | ((unsigned)f2bf(r3) << 16);
    ((uint2*)hout)[(size_t)t * (H1 / 4) + tid] = ov;
}

// ---------- fc2 MFMA: out = relu(h @ W2^T + b2), fp32 out + bf16 copy for att
__global__ __launch_bounds__(128) void k_fc2(const unsigned short* __restrict__ hb,
                                             const unsigned short* __restrict__ w2b,
                                             const float* __restrict__ b2,
                                             float* __restrict__ out,
                                             unsigned short* __restrict__ outb) {
    int wave = threadIdx.x >> 6;
    int lane = threadIdx.x & 63;
    int m0 = blockIdx.x * 16;
    int nbase = wave * 64;
    int ml = lane & 15, quad = lane >> 4;
    const bf16x8* Arow = (const bf16x8*)(hb + (size_t)(m0 + ml) * H1 + quad * 8);
    const bf16x8* Brow[4];
    #pragma unroll
    for (int j = 0; j < 4; j++)
        Brow[j] = (const bf16x8*)(w2b + (size_t)(nbase + j * 16 + ml) * H1 + quad * 8);
    f32x4 acc[4] = {{0,0,0,0},{0,0,0,0},{0,0,0,0},{0,0,0,0}};
    for (int kk = 0; kk < H1 / 32; kk++) {
        bf16x8 a = Arow[kk * 4];
        #pragma unroll
        for (int j = 0; j < 4; j++) {
            bf16x8 b = Brow[j][kk * 4];
            acc[j] = __builtin_amdgcn_mfma_f32_16x16x32_bf16(a, b, acc[j], 0, 0, 0);
        }
    }
    #pragma unroll
    for (int j = 0; j < 4; j++) {
        int col = nbase + j * 16 + ml;
        float bb = b2[col];
        #pragma unroll
        for (int r = 0; r < 4; r++) {
            float v = acc[j][r] + bb;
            v = v > 0.f ? v : 0.f;
            size_t idx = (size_t)(m0 + quad * 4 + r) * H2 + col;
            out[idx] = v;
            outb[idx] = f2bf(v);
        }
    }
}

// ---------- attention MFMA: att = sigmoid(relu(outb @ Wa1^T + ba1) @ Wa2^T + ba2)
// one wave per block; wave = 16 rows x 64 cols, K = 128
__global__ __launch_bounds__(64) void k_att(const unsigned short* __restrict__ outb,
                                            const unsigned short* __restrict__ wa1b,
                                            const float* __restrict__ ba1,
                                            const float* __restrict__ Wa2,
                                            const float* __restrict__ ba2,
                                            float* __restrict__ att) {
    int lane = threadIdx.x & 63;
    int m0 = blockIdx.x * 16;
    int ml = lane & 15, quad = lane >> 4;
    const bf16x8* Arow = (const bf16x8*)(outb + (size_t)(m0 + ml) * H2 + quad * 8);
    const bf16x8* Brow[4];
    #pragma unroll
    for (int j = 0; j < 4; j++)
        Brow[j] = (const bf16x8*)(wa1b + (size_t)(j * 16 + ml) * H2 + quad * 8);
    f32x4 acc[4] = {{0,0,0,0},{0,0,0,0},{0,0,0,0},{0,0,0,0}};
    #pragma unroll
    for (int kk = 0; kk < H2 / 32; kk++) {
        bf16x8 a = Arow[kk * 4];
        #pragma unroll
        for (int j = 0; j < 4; j++) {
            bf16x8 b = Brow[j][kk * 4];
            acc[j] = __builtin_amdgcn_mfma_f32_16x16x32_bf16(a, b, acc[j], 0, 0, 0);
        }
    }
    // z[row=quad*4+r][col=j*16+ml] = acc[j][r]; fold cols with relu + Wa2
    float v0 = 0.f, v1 = 0.f, v2 = 0.f, v3 = 0.f;
    #pragma unroll
    for (int j = 0; j < 4; j++) {
        int col = j * 16 + ml;
        float bb = ba1[col];
        float w2 = Wa2[col];
        float z;
        z = acc[j][0] + bb; v0 += (z > 0.f ? z : 0.f) * w2;
        z = acc[j][1] + bb; v1 += (z > 0.f ? z : 0.f) * w2;
        z = acc[j][2] + bb; v2 += (z > 0.f ? z : 0.f) * w2;
        z = acc[j][3] + bb; v3 += (z > 0.f ? z : 0.f) * w2;
    }
    // butterfly within the 16-lane quad
    #pragma unroll
    for (int d = 1; d < 16; d <<= 1) {
        v0 += __shfl_xor(v0, d, 64);
        v1 += __shfl_xor(v1, d, 64);
        v2 += __shfl_xor(v2, d, 64);
        v3 += __shfl_xor(v3, d, 64);
    }
    if (ml < 4) {
        float v = ml == 0 ? v0 : ml == 1 ? v1 : ml == 2 ? v2 : v3;
        v += ba2[0];
        att[m0 + quad * 4 + ml] = 1.f / (1.f + expf(-v));
    }
}

extern "C" void kernel_launch(void* const* d_in, const int* in_sizes, int n_in,
                              void* d_out, int out_size, void* d_ws, size_t ws_size,
                              hipStream_t stream) {
    const float* x   = (const float*)d_in[0];
    const int*   ei  = (const int*)d_in[1];
    const float* W1  = (const float*)d_in[2];
    const float* b1  = (const float*)d_in[3];
    const float* W2  = (const float*)d_in[4];
    const float* b2  = (const float*)d_in[5];
    const float* Wa1 = (const float*)d_in[6];
    const float* ba1 = (const float*)d_in[7];
    const float* Wa2 = (const float*)d_in[8];
    const float* ba2 = (const float*)d_in[9];
    const int* src = ei;
    const int* tgt = ei + E_EDGES;

    float* out_mat = (float*)d_out;                 // N x 128
    float* att     = out_mat + N_NODES * H2;        // N x 1

    // workspace layout (bf16 buffers as ushort)
    unsigned short* xb   = (unsigned short*)d_ws;                // N*F_IN
    unsigned short* w1b  = xb  + (size_t)N_NODES * F_IN;         // H1*F_IN
    unsigned short* w2b  = w1b + (size_t)H1 * F_IN;              // H2*H1
    unsigned short* wa1b = w2b + (size_t)H2 * H1;                // A1*H2
    unsigned short* h0b  = wa1b + (size_t)A1 * H2;               // N*H1
    unsigned short* h1b  = h0b + (size_t)N_NODES * H1;           // N*H1
    unsigned short* outb = h1b + (size_t)N_NODES * H1;           // N*H2
    float* inv  = (float*)(outb + (size_t)N_NODES * H2);         // N
    int* deg    = (int*)(inv + N_NODES);                         // N
    int* off    = deg + N_NODES;                                 // N+1
    int* cursor = off + N_NODES + 1;                             // N
    int* csr    = cursor + N_NODES;                              // E

    hipMemsetAsync(deg, 0, N_NODES * sizeof(int), stream);

    // dtype converts
    k_f2b<<<(N_NODES * F_IN / 4 + 255) / 256, 256, 0, stream>>>(x, xb, N_NODES * F_IN / 4);
    k_f2bw<<<(H1 * F_IN / 4 + H2 * H1 / 4 + A1 * H2 / 4 + 255) / 256, 256, 0, stream>>>(
        W1, W2, Wa1, w1b, w2b, wa1b);

    // CSR build
    k_deg<<<(E_EDGES + 255) / 256, 256, 0, stream>>>(tgt, deg);
    k_scan<<<1, 1024, 0, stream>>>(deg, off, cursor, inv);
    k_fill<<<(E_EDGES + 255) / 256, 256, 0, stream>>>(src, tgt, cursor, csr);

    // fc1 (MFMA)
    k_fc1<<<N_NODES / 16, 256, 0, stream>>>(xb, w1b, b1, h0b);

    // 2 aggregation passes (bf16)
    k_agg<<<N_NODES, 64, 0, stream>>>(h0b, h1b, off, csr, inv);
    k_agg<<<N_NODES, 64, 0, stream>>>(h1b, h0b, off, csr, inv);

    // fc2 (MFMA) -> out (fp32) + bf16 copy
    k_fc2<<<N_NODES / 16, 128, 0, stream>>>(h0b, w2b, b2, out_mat, outb);

    // attention (MFMA) -> att
    k_att<<<N_NODES / 16, 64, 0, stream>>>(outb, wa1b, ba1, Wa2, ba2, att);
}

// Round 4
// 219.722 us; speedup vs baseline: 1.7899x; 1.0825x over previous
//
#include <hip/hip_runtime.h>
#include <math.h>

#define N_NODES 10000
#define E_EDGES 320000
#define F_IN    384
#define H1      256
#define H2      128
#define A1      64

typedef __attribute__((ext_vector_type(8))) short bf16x8;
typedef __attribute__((ext_vector_type(4))) float f32x4;

static __device__ inline unsigned short f2bf(float f) {
    unsigned u = __float_as_uint(f);
    unsigned r = (u + 0x7fffu + ((u >> 16) & 1u)) >> 16;   // RNE
    return (unsigned short)r;
}

// ---------- fused fp32 -> bf16 converts: x, W1, W2, Wa1 in one launch
__global__ void k_f2ball(const float* __restrict__ x, const float* __restrict__ W1,
                         const float* __restrict__ W2, const float* __restrict__ Wa1,
                         unsigned short* __restrict__ xb, unsigned short* __restrict__ w1b,
                         unsigned short* __restrict__ w2b, unsigned short* __restrict__ wa1b) {
    const int n0 = N_NODES * F_IN / 4;   // 960000
    const int n1 = H1 * F_IN / 4;        // 24576
    const int n2 = H2 * H1 / 4;          // 8192
    const int n3 = A1 * H2 / 4;          // 2048
    int i = blockIdx.x * blockDim.x + threadIdx.x;
    const float4* src;
    ushort4* dst;
    int j;
    if (i < n0)                     { src = (const float4*)x;   dst = (ushort4*)xb;   j = i; }
    else if (i < n0 + n1)           { src = (const float4*)W1;  dst = (ushort4*)w1b;  j = i - n0; }
    else if (i < n0 + n1 + n2)      { src = (const float4*)W2;  dst = (ushort4*)w2b;  j = i - n0 - n1; }
    else if (i < n0 + n1 + n2 + n3) { src = (const float4*)Wa1; dst = (ushort4*)wa1b; j = i - n0 - n1 - n2; }
    else return;
    float4 v = src[j];
    ushort4 o;
    o.x = f2bf(v.x); o.y = f2bf(v.y); o.z = f2bf(v.z); o.w = f2bf(v.w);
    dst[j] = o;
}

// ---------- degree count
__global__ void k_deg(const int* __restrict__ tgt, int* __restrict__ deg) {
    int e = blockIdx.x * blockDim.x + threadIdx.x;
    if (e < E_EDGES) atomicAdd(&deg[tgt[e]], 1);
}

// ---------- exclusive scan over deg (single block, 1024 threads, 10 elems/thread)
__global__ __launch_bounds__(1024) void k_scan(const int* __restrict__ deg, int* __restrict__ off,
                                               int* __restrict__ cursor, float* __restrict__ inv) {
    const int CH = 10;  // 1024*10 = 10240 >= N_NODES
    int tid = threadIdx.x;
    int base = tid * CH;
    int sum = 0;
    int local[CH];
    #pragma unroll
    for (int i = 0; i < CH; i++) {
        int idx = base + i;
        int v = (idx < N_NODES) ? deg[idx] : 0;
        local[i] = sum;
        sum += v;
    }
    __shared__ int sd[1024];
    sd[tid] = sum;
    __syncthreads();
    for (int d = 1; d < 1024; d <<= 1) {
        int v = (tid >= d) ? sd[tid - d] : 0;
        __syncthreads();
        sd[tid] += v;
        __syncthreads();
    }
    int excl = sd[tid] - sum;
    #pragma unroll
    for (int i = 0; i < CH; i++) {
        int idx = base + i;
        if (idx < N_NODES) {
            int o = local[i] + excl;
            off[idx] = o;
            cursor[idx] = o;
            inv[idx] = 1.0f / (float)(deg[idx] + 1);
        }
    }
    if (tid == 1023) off[N_NODES] = sd[1023];
}

// ---------- CSR bin fill
__global__ void k_fill(const int* __restrict__ src, const int* __restrict__ tgt,
                       int* __restrict__ cursor, int* __restrict__ csr) {
    int e = blockIdx.x * blockDim.x + threadIdx.x;
    if (e < E_EDGES) {
        int t = tgt[e];
        int p = atomicAdd(&cursor[t], 1);
        csr[p] = src[e];
    }
}

// ---------- fc1 MFMA: h = relu(x @ W1^T + b1), bf16 in/out
// block = 256 = 4 waves (one 64-col slice each); 32 rows/block (2 row-tiles per wave)
__global__ __launch_bounds__(256) void k_fc1(const unsigned short* __restrict__ xb,
                                             const unsigned short* __restrict__ w1b,
                                             const float* __restrict__ b1,
                                             unsigned short* __restrict__ h) {
    int wave = threadIdx.x >> 6;
    int lane = threadIdx.x & 63;
    int m0 = blockIdx.x * 32;
    int nbase = wave * 64;
    int ml = lane & 15, quad = lane >> 4;
    const bf16x8* Arow0 = (const bf16x8*)(xb + (size_t)(m0 + ml) * F_IN + quad * 8);
    const bf16x8* Arow1 = (const bf16x8*)(xb + (size_t)(m0 + 16 + ml) * F_IN + quad * 8);
    const bf16x8* Brow[4];
    #pragma unroll
    for (int j = 0; j < 4; j++)
        Brow[j] = (const bf16x8*)(w1b + (size_t)(nbase + j * 16 + ml) * F_IN + quad * 8);
    f32x4 acc0[4] = {{0,0,0,0},{0,0,0,0},{0,0,0,0},{0,0,0,0}};
    f32x4 acc1[4] = {{0,0,0,0},{0,0,0,0},{0,0,0,0},{0,0,0,0}};
    for (int kk = 0; kk < F_IN / 32; kk++) {
        bf16x8 a0 = Arow0[kk * 4];
        bf16x8 a1 = Arow1[kk * 4];
        #pragma unroll
        for (int j = 0; j < 4; j++) {
            bf16x8 b = Brow[j][kk * 4];
            acc0[j] = __builtin_amdgcn_mfma_f32_16x16x32_bf16(a0, b, acc0[j], 0, 0, 0);
            acc1[j] = __builtin_amdgcn_mfma_f32_16x16x32_bf16(a1, b, acc1[j], 0, 0, 0);
        }
    }
    #pragma unroll
    for (int j = 0; j < 4; j++) {
        int col = nbase + j * 16 + ml;
        float bb = b1[col];
        #pragma unroll
        for (int r = 0; r < 4; r++) {
            int row0 = m0 + quad * 4 + r;
            int row1 = row0 + 16;
            float v0 = acc0[j][r] + bb;
            v0 = v0 > 0.f ? v0 : 0.f;
            h[(size_t)row0 * H1 + col] = f2bf(v0);
            if (row1 < N_NODES) {
                float v1 = acc1[j][r] + bb;
                v1 = v1 > 0.f ? v1 : 0.f;
                h[(size_t)row1 * H1 + col] = f2bf(v1);
            }
        }
    }
}

// ---------- aggregation (bf16 h): 4 nodes per 256-thread block, unroll-4 edge loop
__global__ __launch_bounds__(256) void k_agg(const unsigned short* __restrict__ hin,
                                             unsigned short* __restrict__ hout,
                                             const int* __restrict__ off,
                                             const int* __restrict__ csr,
                                             const float* __restrict__ inv) {
    int t = blockIdx.x * 4 + (threadIdx.x >> 6);
    int tid = threadIdx.x & 63;
    int s0 = off[t], s1 = off[t + 1];
    const uint2* base = (const uint2*)hin;
    float a0 = 0.f, a1 = 0.f, a2 = 0.f, a3 = 0.f;
    int e = s0;
    for (; e + 4 <= s1; e += 4) {
        int sA = csr[e], sB = csr[e + 1], sC = csr[e + 2], sD = csr[e + 3];
        uint2 vA = base[(size_t)sA * (H1 / 4) + tid];
        uint2 vB = base[(size_t)sB * (H1 / 4) + tid];
        uint2 vC = base[(size_t)sC * (H1 / 4) + tid];
        uint2 vD = base[(size_t)sD * (H1 / 4) + tid];
        a0 += __uint_as_float(vA.x << 16);        a1 += __uint_as_float(vA.x & 0xffff0000u);
        a2 += __uint_as_float(vA.y << 16);        a3 += __uint_as_float(vA.y & 0xffff0000u);
        a0 += __uint_as_float(vB.x << 16);        a1 += __uint_as_float(vB.x & 0xffff0000u);
        a2 += __uint_as_float(vB.y << 16);        a3 += __uint_as_float(vB.y & 0xffff0000u);
        a0 += __uint_as_float(vC.x << 16);        a1 += __uint_as_float(vC.x & 0xffff0000u);
        a2 += __uint_as_float(vC.y << 16);        a3 += __uint_as_float(vC.y & 0xffff0000u);
        a0 += __uint_as_float(vD.x << 16);        a1 += __uint_as_float(vD.x & 0xffff0000u);
        a2 += __uint_as_float(vD.y << 16);        a3 += __uint_as_float(vD.y & 0xffff0000u);
    }
    for (; e < s1; e++) {
        int s = csr[e];
        uint2 v = base[(size_t)s * (H1 / 4) + tid];
        a0 += __uint_as_float(v.x << 16);         a1 += __uint_as_float(v.x & 0xffff0000u);
        a2 += __uint_as_float(v.y << 16);         a3 += __uint_as_float(v.y & 0xffff0000u);
    }
    uint2 sv = base[(size_t)t * (H1 / 4) + tid];
    float iv = 0.3f * inv[t];
    float r0 = 0.7f * __uint_as_float(sv.x << 16)         + iv * a0;
    float r1 = 0.7f * __uint_as_float(sv.x & 0xffff0000u) + iv * a1;
    float r2 = 0.7f * __uint_as_float(sv.y << 16)         + iv * a2;
    float r3 = 0.7f * __uint_as_float(sv.y & 0xffff0000u) + iv * a3;
    uint2 ov;
    ov.x = (unsigned)f2bf(r0) | ((unsigned)f2bf(r1) << 16);
    ov.y = (unsigned)f2bf(r2) | ((unsigned)f2bf(r3) << 16);
    ((uint2*)hout)[(size_t)t * (H1 / 4) + tid] = ov;
}

// ---------- fc2 MFMA: out = relu(h @ W2^T + b2), fp32 out
// block = 128 = 2 waves (one 64-col slice each); 32 rows/block (2 row-tiles per wave)
__global__ __launch_bounds__(128) void k_fc2(const unsigned short* __restrict__ hb,
                                             const unsigned short* __restrict__ w2b,
                                             const float* __restrict__ b2,
                                             float* __restrict__ out) {
    int wave = threadIdx.x >> 6;
    int lane = threadIdx.x & 63;
    int m0 = blockIdx.x * 32;
    int nbase = wave * 64;
    int ml = lane & 15, quad = lane >> 4;
    const bf16x8* Arow0 = (const bf16x8*)(hb + (size_t)(m0 + ml) * H1 + quad * 8);
    const bf16x8* Arow1 = (const bf16x8*)(hb + (size_t)(m0 + 16 + ml) * H1 + quad * 8);
    const bf16x8* Brow[4];
    #pragma unroll
    for (int j = 0; j < 4; j++)
        Brow[j] = (const bf16x8*)(w2b + (size_t)(nbase + j * 16 + ml) * H1 + quad * 8);
    f32x4 acc0[4] = {{0,0,0,0},{0,0,0,0},{0,0,0,0},{0,0,0,0}};
    f32x4 acc1[4] = {{0,0,0,0},{0,0,0,0},{0,0,0,0},{0,0,0,0}};
    for (int kk = 0; kk < H1 / 32; kk++) {
        bf16x8 a0 = Arow0[kk * 4];
        bf16x8 a1 = Arow1[kk * 4];
        #pragma unroll
        for (int j = 0; j < 4; j++) {
            bf16x8 b = Brow[j][kk * 4];
            acc0[j] = __builtin_amdgcn_mfma_f32_16x16x32_bf16(a0, b, acc0[j], 0, 0, 0);
            acc1[j] = __builtin_amdgcn_mfma_f32_16x16x32_bf16(a1, b, acc1[j], 0, 0, 0);
        }
    }
    #pragma unroll
    for (int j = 0; j < 4; j++) {
        int col = nbase + j * 16 + ml;
        float bb = b2[col];
        #pragma unroll
        for (int r = 0; r < 4; r++) {
            int row0 = m0 + quad * 4 + r;
            int row1 = row0 + 16;
            float v0 = acc0[j][r] + bb;
            out[(size_t)row0 * H2 + col] = v0 > 0.f ? v0 : 0.f;
            if (row1 < N_NODES) {
                float v1 = acc1[j][r] + bb;
                out[(size_t)row1 * H2 + col] = v1 > 0.f ? v1 : 0.f;
            }
        }
    }
}

// ---------- attention MFMA: att = sigmoid(relu(out @ Wa1^T + ba1) @ Wa2^T + ba2)
// one wave per block; wave = 16 rows x 64 cols, K = 128; A converted fp32->bf16 inline
__global__ __launch_bounds__(64) void k_att(const float* __restrict__ out,
                                            const unsigned short* __restrict__ wa1b,
                                            const float* __restrict__ ba1,
                                            const float* __restrict__ Wa2,
                                            const float* __restrict__ ba2,
                                            float* __restrict__ att) {
    int lane = threadIdx.x & 63;
    int m0 = blockIdx.x * 16;
    int ml = lane & 15, quad = lane >> 4;
    const float* Arow = out + (size_t)(m0 + ml) * H2 + quad * 8;
    const bf16x8* Brow[4];
    #pragma unroll
    for (int j = 0; j < 4; j++)
        Brow[j] = (const bf16x8*)(wa1b + (size_t)(j * 16 + ml) * H2 + quad * 8);
    f32x4 acc[4] = {{0,0,0,0},{0,0,0,0},{0,0,0,0},{0,0,0,0}};
    #pragma unroll
    for (int kk = 0; kk < H2 / 32; kk++) {
        float4 f0 = *(const float4*)(Arow + kk * 32);
        float4 f1 = *(const float4*)(Arow + kk * 32 + 4);
        bf16x8 a;
        a[0] = (short)f2bf(f0.x); a[1] = (short)f2bf(f0.y);
        a[2] = (short)f2bf(f0.z); a[3] = (short)f2bf(f0.w);
        a[4] = (short)f2bf(f1.x); a[5] = (short)f2bf(f1.y);
        a[6] = (short)f2bf(f1.z); a[7] = (short)f2bf(f1.w);
        #pragma unroll
        for (int j = 0; j < 4; j++) {
            bf16x8 b = Brow[j][kk * 4];
            acc[j] = __builtin_amdgcn_mfma_f32_16x16x32_bf16(a, b, acc[j], 0, 0, 0);
        }
    }
    // z[row=quad*4+r][col=j*16+ml] = acc[j][r]; fold cols with relu + Wa2
    float v0 = 0.f, v1 = 0.f, v2 = 0.f, v3 = 0.f;
    #pragma unroll
    for (int j = 0; j < 4; j++) {
        int col = j * 16 + ml;
        float bb = ba1[col];
        float w2 = Wa2[col];
        float z;
        z = acc[j][0] + bb; v0 += (z > 0.f ? z : 0.f) * w2;
        z = acc[j][1] + bb; v1 += (z > 0.f ? z : 0.f) * w2;
        z = acc[j][2] + bb; v2 += (z > 0.f ? z : 0.f) * w2;
        z = acc[j][3] + bb; v3 += (z > 0.f ? z : 0.f) * w2;
    }
    #pragma unroll
    for (int d = 1; d < 16; d <<= 1) {
        v0 += __shfl_xor(v0, d, 64);
        v1 += __shfl_xor(v1, d, 64);
        v2 += __shfl_xor(v2, d, 64);
        v3 += __shfl_xor(v3, d, 64);
    }
    if (ml < 4) {
        float v = ml == 0 ? v0 : ml == 1 ? v1 : ml == 2 ? v2 : v3;
        v += ba2[0];
        att[m0 + quad * 4 + ml] = 1.f / (1.f + expf(-v));
    }
}

extern "C" void kernel_launch(void* const* d_in, const int* in_sizes, int n_in,
                              void* d_out, int out_size, void* d_ws, size_t ws_size,
                              hipStream_t stream) {
    const float* x   = (const float*)d_in[0];
    const int*   ei  = (const int*)d_in[1];
    const float* W1  = (const float*)d_in[2];
    const float* b1  = (const float*)d_in[3];
    const float* W2  = (const float*)d_in[4];
    const float* b2  = (const float*)d_in[5];
    const float* Wa1 = (const float*)d_in[6];
    const float* ba1 = (const float*)d_in[7];
    const float* Wa2 = (const float*)d_in[8];
    const float* ba2 = (const float*)d_in[9];
    const int* src = ei;
    const int* tgt = ei + E_EDGES;

    float* out_mat = (float*)d_out;                 // N x 128
    float* att     = out_mat + N_NODES * H2;        // N x 1

    // workspace layout (bf16 buffers as ushort)
    unsigned short* xb   = (unsigned short*)d_ws;                // N*F_IN
    unsigned short* w1b  = xb  + (size_t)N_NODES * F_IN;         // H1*F_IN
    unsigned short* w2b  = w1b + (size_t)H1 * F_IN;              // H2*H1
    unsigned short* wa1b = w2b + (size_t)H2 * H1;                // A1*H2
    unsigned short* h0b  = wa1b + (size_t)A1 * H2;               // N*H1
    unsigned short* h1b  = h0b + (size_t)N_NODES * H1;           // N*H1
    float* inv  = (float*)(h1b + (size_t)N_NODES * H1);          // N
    int* deg    = (int*)(inv + N_NODES);                         // N
    int* off    = deg + N_NODES;                                 // N+1
    int* cursor = off + N_NODES + 1;                             // N
    int* csr    = cursor + N_NODES;                              // E

    hipMemsetAsync(deg, 0, N_NODES * sizeof(int), stream);

    // dtype converts (fused)
    {
        int total = N_NODES * F_IN / 4 + H1 * F_IN / 4 + H2 * H1 / 4 + A1 * H2 / 4;
        k_f2ball<<<(total + 255) / 256, 256, 0, stream>>>(x, W1, W2, Wa1, xb, w1b, w2b, wa1b);
    }

    // CSR build
    k_deg<<<(E_EDGES + 255) / 256, 256, 0, stream>>>(tgt, deg);
    k_scan<<<1, 1024, 0, stream>>>(deg, off, cursor, inv);
    k_fill<<<(E_EDGES + 255) / 256, 256, 0, stream>>>(src, tgt, cursor, csr);

    // fc1 (MFMA)
    k_fc1<<<(N_NODES + 31) / 32, 256, 0, stream>>>(xb, w1b, b1, h0b);

    // 2 aggregation passes (bf16)
    k_agg<<<N_NODES / 4, 256, 0, stream>>>(h0b, h1b, off, csr, inv);
    k_agg<<<N_NODES / 4, 256, 0, stream>>>(h1b, h0b, off, csr, inv);

    // fc2 (MFMA) -> out (fp32)
    k_fc2<<<(N_NODES + 31) / 32, 128, 0, stream>>>(h0b, w2b, b2, out_mat);

    // attention (MFMA) -> att
    k_att<<<N_NODES / 16, 64, 0, stream>>>(out_mat, wa1b, ba1, Wa2, ba2, att);
}